// Round 4
// baseline (1906.984 us; speedup 1.0000x reference)
//
#include <hip/hip_runtime.h>
#include <math.h>

#define N_NODES 100000
#define N_EDGES 1600000
#define HID 48
#define ALPHA 0.1f

#define NRANGE 1024              // dst ranges
#define RSIZE  98                // nodes per range (1024*98 = 100352 >= N)
#define NTILE  3                 // src tiles
#define TSIZE  33334
#define NBKT   (NTILE * NRANGE)  // 3072 buckets, tile-major
#define SORTB  64                // sort blocks

typedef unsigned short u16;
typedef unsigned int u32;

__device__ __forceinline__ float bf2f(u16 u) {
    return __uint_as_float(((u32)u) << 16);
}
__device__ __forceinline__ u16 f2bf(float f) {
    u32 b = __float_as_uint(f);
    b += 0x7fff + ((b >> 16) & 1);   // round-to-nearest-even
    return (u16)(b >> 16);
}

// ---------------- lin0: h0 = relu(x @ W0 + b0); writes f32 x0 AND bf16 h0 ----------------
__global__ __launch_bounds__(256) void lin0_k(const float* __restrict__ x, const float* __restrict__ W0,
                                              const float* __restrict__ b0, float* __restrict__ x0f,
                                              u16* __restrict__ h0) {
    int t = blockIdx.x * 256 + threadIdx.x;
    if (t >= N_NODES * HID) return;
    int node = t / HID, f = t % HID;
    float v = b0[f]
            + x[node * 3 + 0] * W0[0 * HID + f]
            + x[node * 3 + 1] * W0[1 * HID + f]
            + x[node * 3 + 2] * W0[2 * HID + f];
    v = v > 0.f ? v : 0.f;
    x0f[t] = v;
    h0[t] = f2bf(v);
}

// ---------------- counting sort phase A: per-block histograms ----------------
__global__ __launch_bounds__(256) void histA_k(const int* __restrict__ src, const int* __restrict__ dst,
                                               int* __restrict__ blockhist) {
    __shared__ int hist[NBKT];
    for (int i = threadIdx.x; i < NBKT; i += 256) hist[i] = 0;
    __syncthreads();
    for (int e = blockIdx.x * 256 + threadIdx.x; e < N_EDGES; e += SORTB * 256) {
        int b = (src[e] / TSIZE) * NRANGE + (dst[e] / RSIZE);
        atomicAdd(&hist[b], 1);
    }
    __syncthreads();
    for (int i = threadIdx.x; i < NBKT; i += 256) blockhist[blockIdx.x * NBKT + i] = hist[i];
}

// ---------------- phase S1: per-bucket exclusive scan across blocks ----------------
__global__ __launch_bounds__(256) void scanS1_k(int* __restrict__ blockhist, int* __restrict__ tot) {
    int b = blockIdx.x * 256 + threadIdx.x;   // 0..NBKT-1
    int run = 0;
#pragma unroll 8
    for (int blk = 0; blk < SORTB; blk++) {
        int t = blockhist[blk * NBKT + b];
        blockhist[blk * NBKT + b] = run;
        run += t;
    }
    tot[b] = run;
}

// ---------------- phase S2: exclusive scan of bucket totals -> bktptr ----------------
__global__ __launch_bounds__(256) void scanS2_k(const int* __restrict__ tot, int* __restrict__ bktptr) {
    __shared__ int sums[256];
    int tid = threadIdx.x;
    int v[NBKT / 256]; int s = 0;
#pragma unroll
    for (int j = 0; j < NBKT / 256; j++) { v[j] = tot[tid * (NBKT / 256) + j]; s += v[j]; }
    sums[tid] = s; __syncthreads();
    for (int off = 1; off < 256; off <<= 1) {
        int t = (tid >= off) ? sums[tid - off] : 0;
        __syncthreads();
        sums[tid] += t;
        __syncthreads();
    }
    int run = (tid > 0) ? sums[tid - 1] : 0;
#pragma unroll
    for (int j = 0; j < NBKT / 256; j++) { bktptr[tid * (NBKT / 256) + j] = run; run += v[j]; }
    if (tid == 255) bktptr[NBKT] = run;
}

// ---------------- phase B: scatter edges (packed src<<8|dstlocal), block-contiguous per bucket ----
__global__ __launch_bounds__(256) void scatB_k(const int* __restrict__ src, const int* __restrict__ dst,
                                               const int* __restrict__ blockhist, const int* __restrict__ bktptr,
                                               u32* __restrict__ edges) {
    __shared__ int cur[NBKT];
    for (int i = threadIdx.x; i < NBKT; i += 256)
        cur[i] = bktptr[i] + blockhist[blockIdx.x * NBKT + i];
    __syncthreads();
    for (int e = blockIdx.x * 256 + threadIdx.x; e < N_EDGES; e += SORTB * 256) {
        int s = src[e], d = dst[e];
        int r = d / RSIZE;
        int b = (s / TSIZE) * NRANGE + r;
        int dl = d - r * RSIZE;
        int pos = atomicAdd(&cur[b], 1);
        edges[pos] = ((u32)s << 8) | (u32)dl;
    }
}

// ---------------- fused layer: LDS-accumulated tiled gather + GCNII combine + matmul + relu ----
// one WG per dst-range (98 nodes); f32 acc lives in LDS; 3 src-tile passes keep gathers L2-local.
__global__ __launch_bounds__(256) void layer2_k(const u16* __restrict__ h_in, const u32* __restrict__ edges,
                                                const int* __restrict__ bktptr, const float* __restrict__ x0,
                                                const float* __restrict__ W, float beta,
                                                u16* __restrict__ h_out) {
    __shared__ float accs[RSIZE * 48];   // 18816 B
    int tid = threadIdx.x, wave = tid >> 6, lane = tid & 63;
    int range = blockIdx.x;
    for (int i = tid; i < RSIZE * 48; i += 256) accs[i] = 0.f;
    __syncthreads();
    int f = lane < 48 ? lane : 47;

    for (int tile = 0; tile < NTILE; tile++) {
        int b = tile * NRANGE + range;
        int e0 = bktptr[b], e1 = bktptr[b + 1];
        for (int base = e0 + wave * 64; base < e1; base += 256) {
            int n = e1 - base; if (n > 64) n = 64;
            u32 p = (lane < n) ? edges[base + lane] : 0u;
            int j = 0;
            for (; j + 8 <= n; j += 8) {
                u32 p0 = __builtin_amdgcn_readlane(p, j + 0);
                u32 p1 = __builtin_amdgcn_readlane(p, j + 1);
                u32 p2 = __builtin_amdgcn_readlane(p, j + 2);
                u32 p3 = __builtin_amdgcn_readlane(p, j + 3);
                u32 p4 = __builtin_amdgcn_readlane(p, j + 4);
                u32 p5 = __builtin_amdgcn_readlane(p, j + 5);
                u32 p6 = __builtin_amdgcn_readlane(p, j + 6);
                u32 p7 = __builtin_amdgcn_readlane(p, j + 7);
                float v0 = bf2f(h_in[(p0 >> 8) * 48 + f]);
                float v1 = bf2f(h_in[(p1 >> 8) * 48 + f]);
                float v2 = bf2f(h_in[(p2 >> 8) * 48 + f]);
                float v3 = bf2f(h_in[(p3 >> 8) * 48 + f]);
                float v4 = bf2f(h_in[(p4 >> 8) * 48 + f]);
                float v5 = bf2f(h_in[(p5 >> 8) * 48 + f]);
                float v6 = bf2f(h_in[(p6 >> 8) * 48 + f]);
                float v7 = bf2f(h_in[(p7 >> 8) * 48 + f]);
                if (lane < 48) {
                    atomicAdd(&accs[(p0 & 255u) * 48 + lane], v0);
                    atomicAdd(&accs[(p1 & 255u) * 48 + lane], v1);
                    atomicAdd(&accs[(p2 & 255u) * 48 + lane], v2);
                    atomicAdd(&accs[(p3 & 255u) * 48 + lane], v3);
                    atomicAdd(&accs[(p4 & 255u) * 48 + lane], v4);
                    atomicAdd(&accs[(p5 & 255u) * 48 + lane], v5);
                    atomicAdd(&accs[(p6 & 255u) * 48 + lane], v6);
                    atomicAdd(&accs[(p7 & 255u) * 48 + lane], v7);
                }
            }
            for (; j < n; j++) {
                u32 pj = __builtin_amdgcn_readlane(p, j);
                float v = bf2f(h_in[(pj >> 8) * 48 + f]);
                if (lane < 48) atomicAdd(&accs[(pj & 255u) * 48 + lane], v);
            }
        }
    }
    __syncthreads();

    // epilogue: t = (1-a)*agg + a*x0; h_out = relu((1-b)*t + b*(t@W))
    for (int i = wave; i < RSIZE; i += 4) {
        int node = range * RSIZE + i;
        if (node >= N_NODES) break;
        if (lane < 48) {
            float t = (1.f - ALPHA) * accs[i * 48 + lane] + ALPHA * x0[node * 48 + lane];
            accs[i * 48 + lane] = t;           // wave-synchronous: same wave reads below
            const float4* t4 = (const float4*)&accs[i * 48];
            float s2 = 0.f;
#pragma unroll
            for (int k4 = 0; k4 < 12; k4++) {
                float4 tv = t4[k4];
                s2 += tv.x * W[(4 * k4 + 0) * 48 + lane] + tv.y * W[(4 * k4 + 1) * 48 + lane]
                    + tv.z * W[(4 * k4 + 2) * 48 + lane] + tv.w * W[(4 * k4 + 3) * 48 + lane];
            }
            float o = (1.f - beta) * t + beta * s2;
            h_out[node * 48 + lane] = f2bf(o > 0.f ? o : 0.f);
        }
    }
}

// ---------------- final: out = log_softmax(h @ W1 + b1) ----------------
__global__ __launch_bounds__(256) void final_k(const u16* __restrict__ h, const float* __restrict__ W1,
                                               const float* __restrict__ b1, float* __restrict__ out) {
    __shared__ float tbuf[4][48];
    int tid = threadIdx.x, wave = tid >> 6, lane = tid & 63;
    int node = blockIdx.x * 4 + wave;
    int f = lane < 48 ? lane : 0;
    if (lane < 48) tbuf[wave][lane] = bf2f(h[node * 48 + lane]);
    float v = -INFINITY;
    {
        const float4* t4 = (const float4*)tbuf[wave];
        float s = b1[f];
#pragma unroll
        for (int k4 = 0; k4 < 12; k4++) {
            float4 tv = t4[k4];
            s += tv.x * W1[(4 * k4 + 0) * 48 + f] + tv.y * W1[(4 * k4 + 1) * 48 + f]
               + tv.z * W1[(4 * k4 + 2) * 48 + f] + tv.w * W1[(4 * k4 + 3) * 48 + f];
        }
        if (lane < 48) v = s;
    }
    float m = v;
    for (int off = 32; off >= 1; off >>= 1) m = fmaxf(m, __shfl_xor(m, off));
    float ex = (lane < 48) ? expf(v - m) : 0.f;
    float sum = ex;
    for (int off = 32; off >= 1; off >>= 1) sum += __shfl_xor(sum, off);
    if (lane < 48) out[node * 48 + lane] = v - m - logf(sum);
}

extern "C" void kernel_launch(void* const* d_in, const int* in_sizes, int n_in,
                              void* d_out, int out_size, void* d_ws, size_t ws_size,
                              hipStream_t stream) {
    const float* x     = (const float*)d_in[0];
    const int*   ei    = (const int*)d_in[1];
    const float* W0    = (const float*)d_in[2];
    const float* b0    = (const float*)d_in[3];
    const float* convW = (const float*)d_in[4];
    const float* W1    = (const float*)d_in[5];
    const float* b1    = (const float*)d_in[6];
    float* out = (float*)d_out;
    const int* src = ei;            // edge_index[0]
    const int* dst = ei + N_EDGES;  // edge_index[1]

    char* ws = (char*)d_ws;
    size_t off = 0;
    float* x0   = (float*)(ws + off); off += (size_t)N_NODES * 48 * 4;     // 19.2 MB
    u16* hA     = (u16*)(ws + off);   off += (size_t)N_NODES * 48 * 2;     // 9.6 MB
    u16* hB     = (u16*)(ws + off);   off += (size_t)N_NODES * 48 * 2;     // 9.6 MB
    u32* edges  = (u32*)(ws + off);   off += (size_t)N_EDGES * 4;          // 6.4 MB
    int* blockhist = (int*)(ws + off); off += (size_t)SORTB * NBKT * 4;    // 786 KB
    off = (off + 255) & ~(size_t)255;
    int* bktptr = (int*)(ws + off);   off += (size_t)(NBKT + 1) * 4;
    off = (off + 255) & ~(size_t)255;
    int* tot    = (int*)(ws + off);   off += (size_t)NBKT * 4;

    lin0_k<<<18750, 256, 0, stream>>>(x, W0, b0, x0, hA);
    histA_k<<<SORTB, 256, 0, stream>>>(src, dst, blockhist);
    scanS1_k<<<NBKT / 256, 256, 0, stream>>>(blockhist, tot);
    scanS2_k<<<1, 256, 0, stream>>>(tot, bktptr);
    scatB_k<<<SORTB, 256, 0, stream>>>(src, dst, blockhist, bktptr, edges);

    const float betas[4] = { logf(1.5f), logf(1.25f), logf(7.f / 6.f), logf(1.125f) };

    u16* hin = hA; u16* hout = hB;
    for (int l = 0; l < 4; l++) {
        layer2_k<<<NRANGE, 256, 0, stream>>>(hin, edges, bktptr, x0, convW + l * 2304, betas[l], hout);
        u16* tmp = hin; hin = hout; hout = tmp;
    }
    final_k<<<25000, 256, 0, stream>>>(hin, W1, b1, out);
}